// Round 20
// baseline (102.919 us; speedup 1.0000x reference)
//
#include <hip/hip_runtime.h>

#define B_ 4
#define C_ 64
#define H_ 256
#define W_ 256
#define KK 9

typedef __attribute__((ext_vector_type(8))) short short8;
typedef __attribute__((ext_vector_type(4))) float float4_;
typedef __attribute__((ext_vector_type(2))) float float2_;

static __device__ __forceinline__ unsigned short f2bf(float f) {
    unsigned int u = __builtin_bit_cast(unsigned int, f);
    unsigned int r = (u + 0x7fffu + ((u >> 16) & 1u)) >> 16;  // RNE
    return (unsigned short)r;
}
static __device__ __forceinline__ float bf2f(short s) {
    return __builtin_bit_cast(float, (unsigned int)((unsigned short)s) << 16);
}
// async global->LDS, 16B per lane; LDS dest is WAVE-UNIFORM base + lane*16 (HW adds it)
static __device__ __forceinline__ void gld16(const unsigned short* gp, unsigned short* lbase) {
    __builtin_amdgcn_global_load_lds(
        (const __attribute__((address_space(1))) unsigned int*)gp,
        (__attribute__((address_space(3))) unsigned int*)lbase, 16, 0, 0);
}
// att tile alias inside xs (conv5): rows 0 and 19 are never read by perpix taps.
static __device__ __forceinline__ int att_idx(int pl, int j) {
    return (pl < 128) ? (pl * 9 + j) : (24320 + (pl - 128) * 9 + j);
}

// ---------------- Kernel A: NCHW fp32 -> NHWC bf16 (LDS transpose, packed writes) ----------------
__global__ __launch_bounds__(256) void nchw2nhwc(
    const float* __restrict__ x, unsigned short* __restrict__ xh)
{
    __shared__ unsigned short t[256 * 66];
    int row = blockIdx.x;                   // b*256 + h
    int b = row >> 8;
    const float* src = x + ((size_t)b * 64) * 65536 + (size_t)(row & 255) * 256;
    int tid = threadIdx.x;

    #pragma unroll 8
    for (int c = 0; c < 64; c += 2) {
        unsigned int lo = f2bf(src[(size_t)c * 65536 + tid]);
        unsigned int hi = f2bf(src[(size_t)(c + 1) * 65536 + tid]);
        *(unsigned int*)(&t[tid * 66 + c]) = lo | (hi << 16);
    }
    __syncthreads();

    unsigned short* dst = xh + (size_t)row * 256 * 64;
    #pragma unroll
    for (int it = 0; it < 8; ++it) {
        int idx = it * 256 + tid;
        int pix = idx >> 3, g = idx & 7;
        short8 v = *(const short8*)(&t[pix * 66 + g * 8]);
        *(short8*)(dst + (size_t)pix * 64 + g * 8) = v;
    }
}

// ---------------- Kernel B: merged weight transforms ----------------
__global__ __launch_bounds__(256) void wprep_all(
    const float* __restrict__ w5, const float* __restrict__ w3,
    unsigned short* __restrict__ wb, unsigned short* __restrict__ wb3)
{
    int i = blockIdx.x * 256 + threadIdx.x;   // 25600 + 9216 = 34816
    if (i < 25600) {
        int tap = i >> 10;
        int q = (i >> 7) & 7;
        int n = (i >> 3) & 15;
        int e = i & 7;
        int c = q * 8 + e;
        int di = tap / 5, dj = tap % 5;
        float v = (n < KK) ? w5[((n * C_ + c) * 5 + di) * 5 + dj] : 0.f;
        wb[i] = f2bf(v);
    } else if (i < 34816) {
        int k = i - 25600;
        int tap = k >> 10;
        int q = (k >> 7) & 7;
        int n = (k >> 3) & 15;
        int e = k & 7;
        int c = q * 8 + e;
        int di = tap / 3, dj = tap % 3;
        float v = (n < KK) ? w3[((n * C_ + c) * 3 + di) * 3 + dj] : 0.f;
        wb3[k] = f2bf(v);
    }
}

// ---------------- Kernel C: FUSED conv5+tanh (MFMA) + per-pixel filter, 512 threads ----------------
__global__ __launch_bounds__(512) void conv5_perpix(
    const unsigned short* __restrict__ xh,   // [B][H][W][64] bf16
    const unsigned short* __restrict__ wb,   // [25][8][16][8] bf16
    const float* __restrict__ bias,
    float* __restrict__ attf,                // [B][64][H][W] f32 (output)
    unsigned short* __restrict__ dh)         // [B][H][W][64] bf16
{
    __shared__ __align__(16) unsigned short xs[20 * 20 * 64];  // 51200 B -> 3 blocks/CU

    int tid = threadIdx.x;
    int bx = blockIdx.x & 15;
    int by = (blockIdx.x >> 4) & 15;
    int b  = blockIdx.x >> 8;
    int h0 = by * 16, w0 = bx * 16;
    bool interior = (bx >= 1 && bx <= 14 && by >= 1 && by <= 14);

    int lane = tid & 63;
    int wid  = tid >> 6;      // 0..7

    // ---- phase 1: stage x (swizzle: slot s of pixel pix holds chunk s^(pix&7)) ----
    if (interior) {
        int p = (lane & 7) ^ ((lane >> 3) & 7);
        for (int it = wid; it < 50; it += 8) {
            int pix = it * 8 + (lane >> 3);
            int py = pix / 20, px = pix % 20;
            int gy = h0 + py - 2, gx = w0 + px - 2;
            const unsigned short* g = xh + ((size_t)((b * 256 + gy) * 256 + gx) * 64 + p * 8);
            gld16(g, &xs[it * 512]);
        }
    } else {
        for (int q = tid; q < 400 * 8; q += 512) {
            int p = q & 7;
            int pix = q >> 3;
            int py = pix / 20, px = pix % 20;
            int gy = h0 + py - 2, gx = w0 + px - 2;
            short8 v = (short8)0;
            if (gy >= 0 && gy < H_ && gx >= 0 && gx < W_)
                v = *(const short8*)(xh + ((size_t)((b * 256 + gy) * 256 + gx) * 64 + p * 8));
            *(short8*)(&xs[(pix << 6) + ((p ^ (pix & 7)) << 3)]) = v;
        }
    }
    __syncthreads();

    // ---- phase 2: conv5 via MFMA (wave owns output rows wid*2 + {0,1}) ----
    int m16  = lane & 15;
    int lq   = lane >> 4;

    float4_ acc[2];
    float bj = (m16 < KK) ? bias[m16] : 0.f;
    #pragma unroll
    for (int r = 0; r < 2; ++r) acc[r] = (float4_){bj, bj, bj, bj};

    #pragma unroll
    for (int dj = 0; dj < 5; ++dj) {
        short8 bfr[5][2];
        #pragma unroll
        for (int di = 0; di < 5; ++di) {
            int tap = di * 5 + dj;
            bfr[di][0] = *(const short8*)(wb + (((tap * 8 + lq) * 16 + m16) * 8));
            bfr[di][1] = *(const short8*)(wb + (((tap * 8 + 4 + lq) * 16 + m16) * 8));
        }
        int px = m16 + dj;
        #pragma unroll
        for (int s = 0; s < 6; ++s) {
            int pix = (wid * 2 + s) * 20 + px;
            int c0 = lq ^ (pix & 7);
            short8 a0 = *(const short8*)(&xs[(pix << 6) + (c0 << 3)]);
            short8 a1 = *(const short8*)(&xs[(pix << 6) + ((c0 ^ 4) << 3)]);
            #pragma unroll
            for (int di = 0; di < 5; ++di) {
                int r = s - di;
                if (r < 0 || r > 1) continue;
                acc[r] = __builtin_amdgcn_mfma_f32_16x16x32_bf16(a0, bfr[di][0], acc[r], 0, 0, 0);
                acc[r] = __builtin_amdgcn_mfma_f32_16x16x32_bf16(a1, bfr[di][1], acc[r], 0, 0, 0);
            }
        }
    }
    __syncthreads();   // all MFMA reads of xs rows 0/19 complete before att overwrites them

    // att (tanh, bf16) -> xs dead rows [pixel16x16][9]
    if (m16 < KK) {
        #pragma unroll
        for (int r = 0; r < 2; ++r) {
            #pragma unroll
            for (int reg = 0; reg < 4; ++reg) {
                int pl = (wid * 2 + r) * 16 + lq * 4 + reg;
                xs[att_idx(pl, m16)] = f2bf(tanhf(acc[r][reg]));
            }
        }
    }
    __syncthreads();

    // ---- phase 3: perpix on interior 16x16, packed-f32 (v_pk_fma_f32) inner loop ----
    #pragma unroll
    for (int it = 0; it < 4; ++it) {
        int idx = it * 512 + tid;        // (pl, g): 256 pix x 8 chunks
        int g = idx & 7;
        int pl = idx >> 3;
        int py = pl >> 4, px = pl & 15;  // local 16x16
        int hw = ((h0 + py) << 8) | (w0 + px);

        float a[KK];
        #pragma unroll
        for (int j = 0; j < KK; ++j) a[j] = bf2f(xs[att_idx(pl, j)]);

        float2_ s2[4];
        #pragma unroll
        for (int k = 0; k < 4; ++k) s2[k] = (float2_){0.f, 0.f};
        unsigned int cen[4] = {0, 0, 0, 0};

        #pragma unroll
        for (int di = 0; di < 3; ++di) {
            #pragma unroll
            for (int dj = 0; dj < 3; ++dj) {
                int tp = (py + 1 + di) * 20 + (px + 1 + dj);   // xs coords (origin -2), rows 1..18
                int c = g ^ (tp & 7);
                const unsigned int* vu = (const unsigned int*)(&xs[(tp << 6) + (c << 3)]);
                unsigned int uu[4];
                #pragma unroll
                for (int k = 0; k < 4; ++k) uu[k] = vu[k];
                if (di == 1 && dj == 1) {
                    #pragma unroll
                    for (int k = 0; k < 4; ++k) cen[k] = uu[k];
                }
                float aj = a[di * 3 + dj];
                float2_ aj2 = {aj, aj};
                #pragma unroll
                for (int k = 0; k < 4; ++k) {
                    float2_ xv = {__builtin_bit_cast(float, uu[k] << 16),
                                  __builtin_bit_cast(float, uu[k] & 0xffff0000u)};
                    s2[k] += xv * aj2;   // -> v_pk_fma_f32
                }
            }
        }

        #pragma unroll
        for (int k = 0; k < 4; ++k) {
            attf[((b * C_ + g * 8 + 2 * k)     << 16) | hw] = s2[k][0];
            attf[((b * C_ + g * 8 + 2 * k + 1) << 16) | hw] = s2[k][1];
        }

        short8 dv;
        #pragma unroll
        for (int k = 0; k < 4; ++k) {
            float xc0 = __builtin_bit_cast(float, cen[k] << 16);
            float xc1 = __builtin_bit_cast(float, cen[k] & 0xffff0000u);
            dv[2 * k]     = (short)f2bf(xc0 - s2[k][0]);
            dv[2 * k + 1] = (short)f2bf(xc1 - s2[k][1]);
        }
        *(short8*)(dh + ((size_t)((b << 16) | hw) * 64 + g * 8)) = dv;
    }
}

// ---------------- Kernel E: conv3 (64 -> 9) on d via bf16 MFMA, 512 threads ----------------
__global__ __launch_bounds__(512) void conv3_mfma(
    const unsigned short* __restrict__ dh,   // [B][H][W][64] bf16
    const unsigned short* __restrict__ wb3,  // [9][8][16][8] bf16
    const float* __restrict__ bias,
    unsigned short* __restrict__ r1h)        // [B][9][H][W] bf16
{
    __shared__ __align__(16) unsigned short xs[328 * 64];  // 41984 B (324 pix + 4 pad)

    int tid = threadIdx.x;
    int bx = blockIdx.x & 15;
    int by = (blockIdx.x >> 4) & 15;
    int b  = blockIdx.x >> 8;
    int h0 = by * 16, w0 = bx * 16;
    bool interior = (bx >= 1 && bx <= 14 && by >= 1 && by <= 14);

    int lane = tid & 63;
    int wid  = tid >> 6;      // 0..7

    if (interior) {
        int p = (lane & 7) ^ ((lane >> 3) & 7);
        for (int it = wid; it < 41; it += 8) {     // 328 pixels (4 pad, in-bounds reads)
            int pix = it * 8 + (lane >> 3);
            int py = pix / 18, px = pix - py * 18;
            int gy = h0 + py - 1, gx = w0 + px - 1;
            const unsigned short* g = dh + ((size_t)((b * 256 + gy) * 256 + gx) * 64 + p * 8);
            gld16(g, &xs[it * 512]);
        }
    } else {
        for (int q = tid; q < 324 * 8; q += 512) {
            int p = q & 7;
            int pix = q >> 3;
            int py = pix / 18, px = pix - py * 18;
            int gy = h0 + py - 1, gx = w0 + px - 1;
            short8 v = (short8)0;
            if (gy >= 0 && gy < H_ && gx >= 0 && gx < W_)
                v = *(const short8*)(dh + ((size_t)((b * 256 + gy) * 256 + gx) * 64 + p * 8));
            *(short8*)(&xs[(pix << 6) + ((p ^ (pix & 7)) << 3)]) = v;
        }
    }
    __syncthreads();

    int m16  = lane & 15;
    int lq   = lane >> 4;

    float4_ acc[2];
    float bj = (m16 < KK) ? bias[m16] : 0.f;
    #pragma unroll
    for (int r = 0; r < 2; ++r) acc[r] = (float4_){bj, bj, bj, bj};

    #pragma unroll
    for (int dj = 0; dj < 3; ++dj) {
        short8 bfr[3][2];
        #pragma unroll
        for (int di = 0; di < 3; ++di) {
            int tap = di * 3 + dj;
            bfr[di][0] = *(const short8*)(wb3 + (((tap * 8 + lq) * 16 + m16) * 8));
            bfr[di][1] = *(const short8*)(wb3 + (((tap * 8 + 4 + lq) * 16 + m16) * 8));
        }
        int px = m16 + dj;
        #pragma unroll
        for (int s = 0; s < 4; ++s) {
            int pix = (wid * 2 + s) * 18 + px;
            int c0 = lq ^ (pix & 7);
            short8 a0 = *(const short8*)(&xs[(pix << 6) + (c0 << 3)]);
            short8 a1 = *(const short8*)(&xs[(pix << 6) + ((c0 ^ 4) << 3)]);
            #pragma unroll
            for (int di = 0; di < 3; ++di) {
                int r = s - di;
                if (r < 0 || r > 1) continue;
                acc[r] = __builtin_amdgcn_mfma_f32_16x16x32_bf16(a0, bfr[di][0], acc[r], 0, 0, 0);
                acc[r] = __builtin_amdgcn_mfma_f32_16x16x32_bf16(a1, bfr[di][1], acc[r], 0, 0, 0);
            }
        }
    }

    if (m16 < KK) {
        #pragma unroll
        for (int r = 0; r < 2; ++r) {
            int py = h0 + wid * 2 + r;
            #pragma unroll
            for (int reg = 0; reg < 4; ++reg) {
                int px = w0 + lq * 4 + reg;
                r1h[((b * KK + m16) << 16) | (py << 8) | px] = f2bf(acc[r][reg]);
            }
        }
    }
}

// ---------------- Kernel F: 3x3 conv (9 -> 9) + tanh, bf16 in ----------------
__global__ __launch_bounds__(256) void conv3_tanh9(
    const unsigned short* __restrict__ r1h, const float* __restrict__ w,
    const float* __restrict__ bias, float* __restrict__ out)
{
    const int TW = 32, TH = 8, PW = 34, PH = 10;
    __shared__ float lds[KK][PH][PW];

    int tid = threadIdx.x;
    int tx = tid & 31, ty = tid >> 5;
    int bw = blockIdx.x & 7;
    int bh = (blockIdx.x >> 3) & 31;
    int b  = blockIdx.x >> 8;
    int h0 = bh * TH, w0 = bw * TW;

    for (int idx = tid; idx < KK * PH * PW; idx += 256) {
        int px = idx % PW;
        int py = (idx / PW) % PH;
        int ch = idx / (PW * PH);
        int gy = h0 + py - 1, gx = w0 + px - 1;
        float v = 0.f;
        if (gy >= 0 && gy < H_ && gx >= 0 && gx < W_)
            v = bf2f(r1h[((b * KK + ch) << 16) | (gy << 8) | gx]);
        lds[ch][py][px] = v;
    }
    __syncthreads();

    float acc[KK];
    #pragma unroll
    for (int j = 0; j < KK; ++j) acc[j] = bias[j];

    for (int cin = 0; cin < KK; ++cin) {
        #pragma unroll
        for (int di = 0; di < 3; ++di) {
            #pragma unroll
            for (int dj = 0; dj < 3; ++dj) {
                float xv = lds[cin][ty + di][tx + dj];
                #pragma unroll
                for (int j = 0; j < KK; ++j)
                    acc[j] += xv * w[((j * KK + cin) * 3 + di) * 3 + dj];
            }
        }
    }

    int h = h0 + ty, wq = w0 + tx;
    #pragma unroll
    for (int j = 0; j < KK; ++j)
        out[((b * KK + j) << 16) | (h << 8) | wq] = tanhf(acc[j]);
}

extern "C" void kernel_launch(void* const* d_in, const int* in_sizes, int n_in,
                              void* d_out, int out_size, void* d_ws, size_t ws_size,
                              hipStream_t stream) {
    const float* feature = (const float*)d_in[0];
    const float* w_sharp = (const float*)d_in[1];
    const float* b_sharp = (const float*)d_in[2];
    const float* w_r1    = (const float*)d_in[3];
    const float* b_r1    = (const float*)d_in[4];
    const float* w_r2    = (const float*)d_in[5];
    const float* b_r2    = (const float*)d_in[6];

    float* out_reblur = (float*)d_out;                          // [4,9,256,256]
    float* out_attf   = out_reblur + (size_t)B_ * KK * H_ * W_; // [4,64,256,256]

    char* ws = (char*)d_ws;
    unsigned short* xh   = (unsigned short*)ws;                  // 33554432 B
    unsigned short* dh   = (unsigned short*)(ws + 33554432);     // 33554432 B
    unsigned short* wb   = (unsigned short*)(ws + 67108864);     // 51200 -> pad 65536
    unsigned short* wb3  = (unsigned short*)(ws + 67174400);     // 18432 -> pad 32768
    unsigned short* r1h  = (unsigned short*)(ws + 67207168);     // 4718592 B bf16

    nchw2nhwc<<<1024, 256, 0, stream>>>(feature, xh);
    wprep_all<<<136, 256, 0, stream>>>(w_sharp, w_r1, wb, wb3);
    conv5_perpix<<<1024, 512, 0, stream>>>(xh, wb, b_sharp, out_attf, dh);
    conv3_mfma<<<1024, 512, 0, stream>>>(dh, wb3, b_r1, r1h);
    conv3_tanh9<<<1024, 256, 0, stream>>>(r1h, w_r2, b_r2, out_reblur);
}

// Round 21
// 100.663 us; speedup vs baseline: 1.0224x; 1.0224x over previous
//
#include <hip/hip_runtime.h>

#define B_ 4
#define C_ 64
#define H_ 256
#define W_ 256
#define KK 9

typedef __attribute__((ext_vector_type(8))) short short8;
typedef __attribute__((ext_vector_type(4))) float float4_;

static __device__ __forceinline__ unsigned short f2bf(float f) {
    unsigned int u = __builtin_bit_cast(unsigned int, f);
    unsigned int r = (u + 0x7fffu + ((u >> 16) & 1u)) >> 16;  // RNE
    return (unsigned short)r;
}
static __device__ __forceinline__ float bf2f(short s) {
    return __builtin_bit_cast(float, (unsigned int)((unsigned short)s) << 16);
}
// async global->LDS, 16B per lane; LDS dest is WAVE-UNIFORM base + lane*16 (HW adds it)
static __device__ __forceinline__ void gld16(const unsigned short* gp, unsigned short* lbase) {
    __builtin_amdgcn_global_load_lds(
        (const __attribute__((address_space(1))) unsigned int*)gp,
        (__attribute__((address_space(3))) unsigned int*)lbase, 16, 0, 0);
}
// att tile alias inside xs (conv5): rows 0 and 19 are never read by perpix taps.
static __device__ __forceinline__ int att_idx(int pl, int j) {
    return (pl < 128) ? (pl * 9 + j) : (24320 + (pl - 128) * 9 + j);
}

// ---------------- Kernel A: NCHW fp32 -> NHWC bf16 transpose + co-scheduled weight prep ----------------
// Blocks 0..1023: row transpose (unchanged). Blocks 1024..1159: wprep items
// (unpacked [tap][8][16][8] layout, identical to the proven round-19 wb/wb3).
__global__ __launch_bounds__(256) void nchw2nhwc(
    const float* __restrict__ x, unsigned short* __restrict__ xh,
    const float* __restrict__ w5, const float* __restrict__ w3,
    unsigned short* __restrict__ wb, unsigned short* __restrict__ wb3)
{
    int tid = threadIdx.x;
    if (blockIdx.x >= 1024) {
        int i = (blockIdx.x - 1024) * 256 + tid;   // 25600 + 9216 = 34816 items
        if (i < 25600) {
            int tap = i >> 10;
            int q = (i >> 7) & 7;
            int n = (i >> 3) & 15;
            int e = i & 7;
            int c = q * 8 + e;
            int di = tap / 5, dj = tap % 5;
            float v = (n < KK) ? w5[((n * C_ + c) * 5 + di) * 5 + dj] : 0.f;
            wb[i] = f2bf(v);
        } else if (i < 34816) {
            int k = i - 25600;
            int tap = k >> 10;
            int q = (k >> 7) & 7;
            int n = (k >> 3) & 15;
            int e = k & 7;
            int c = q * 8 + e;
            int di = tap / 3, dj = tap % 3;
            float v = (n < KK) ? w3[((n * C_ + c) * 3 + di) * 3 + dj] : 0.f;
            wb3[k] = f2bf(v);
        }
        return;
    }

    __shared__ unsigned short t[256 * 66];
    int row = blockIdx.x;                   // b*256 + h
    int b = row >> 8;
    const float* src = x + ((size_t)b * 64) * 65536 + (size_t)(row & 255) * 256;

    #pragma unroll 8
    for (int c = 0; c < 64; c += 2) {
        unsigned int lo = f2bf(src[(size_t)c * 65536 + tid]);
        unsigned int hi = f2bf(src[(size_t)(c + 1) * 65536 + tid]);
        *(unsigned int*)(&t[tid * 66 + c]) = lo | (hi << 16);
    }
    __syncthreads();

    unsigned short* dst = xh + (size_t)row * 256 * 64;
    #pragma unroll
    for (int it = 0; it < 8; ++it) {
        int idx = it * 256 + tid;
        int pix = idx >> 3, g = idx & 7;
        short8 v = *(const short8*)(&t[pix * 66 + g * 8]);
        *(short8*)(dst + (size_t)pix * 64 + g * 8) = v;
    }
}

// ---------------- Kernel C: FUSED conv5+tanh (MFMA) + per-pixel filter, 512 threads ----------------
__global__ __launch_bounds__(512) void conv5_perpix(
    const unsigned short* __restrict__ xh,   // [B][H][W][64] bf16
    const unsigned short* __restrict__ wb,   // [25][8][16][8] bf16
    const float* __restrict__ bias,
    float* __restrict__ attf,                // [B][64][H][W] f32 (output)
    unsigned short* __restrict__ dh)         // [B][H][W][64] bf16
{
    __shared__ __align__(16) unsigned short xs[20 * 20 * 64];  // 51200 B -> 3 blocks/CU

    int tid = threadIdx.x;
    int bx = blockIdx.x & 15;
    int by = (blockIdx.x >> 4) & 15;
    int b  = blockIdx.x >> 8;
    int h0 = by * 16, w0 = bx * 16;
    bool interior = (bx >= 1 && bx <= 14 && by >= 1 && by <= 14);

    int lane = tid & 63;
    int wid  = tid >> 6;      // 0..7

    // ---- phase 1: stage x (swizzle: slot s of pixel pix holds chunk s^(pix&7)) ----
    if (interior) {
        int p = (lane & 7) ^ ((lane >> 3) & 7);
        for (int it = wid; it < 50; it += 8) {
            int pix = it * 8 + (lane >> 3);
            int py = pix / 20, px = pix % 20;
            int gy = h0 + py - 2, gx = w0 + px - 2;
            const unsigned short* g = xh + ((size_t)((b * 256 + gy) * 256 + gx) * 64 + p * 8);
            gld16(g, &xs[it * 512]);
        }
    } else {
        for (int q = tid; q < 400 * 8; q += 512) {
            int p = q & 7;
            int pix = q >> 3;
            int py = pix / 20, px = pix % 20;
            int gy = h0 + py - 2, gx = w0 + px - 2;
            short8 v = (short8)0;
            if (gy >= 0 && gy < H_ && gx >= 0 && gx < W_)
                v = *(const short8*)(xh + ((size_t)((b * 256 + gy) * 256 + gx) * 64 + p * 8));
            *(short8*)(&xs[(pix << 6) + ((p ^ (pix & 7)) << 3)]) = v;
        }
    }
    __syncthreads();

    // ---- phase 2: conv5 via MFMA (wave owns output rows wid*2 + {0,1}) ----
    int m16  = lane & 15;
    int lq   = lane >> 4;

    float4_ acc[2];
    float bj = (m16 < KK) ? bias[m16] : 0.f;
    #pragma unroll
    for (int r = 0; r < 2; ++r) acc[r] = (float4_){bj, bj, bj, bj};

    #pragma unroll
    for (int dj = 0; dj < 5; ++dj) {
        short8 bfr[5][2];
        #pragma unroll
        for (int di = 0; di < 5; ++di) {
            int tap = di * 5 + dj;
            bfr[di][0] = *(const short8*)(wb + (((tap * 8 + lq) * 16 + m16) * 8));
            bfr[di][1] = *(const short8*)(wb + (((tap * 8 + 4 + lq) * 16 + m16) * 8));
        }
        int px = m16 + dj;
        #pragma unroll
        for (int s = 0; s < 6; ++s) {
            int pix = (wid * 2 + s) * 20 + px;
            int c0 = lq ^ (pix & 7);
            short8 a0 = *(const short8*)(&xs[(pix << 6) + (c0 << 3)]);
            short8 a1 = *(const short8*)(&xs[(pix << 6) + ((c0 ^ 4) << 3)]);
            #pragma unroll
            for (int di = 0; di < 5; ++di) {
                int r = s - di;
                if (r < 0 || r > 1) continue;
                acc[r] = __builtin_amdgcn_mfma_f32_16x16x32_bf16(a0, bfr[di][0], acc[r], 0, 0, 0);
                acc[r] = __builtin_amdgcn_mfma_f32_16x16x32_bf16(a1, bfr[di][1], acc[r], 0, 0, 0);
            }
        }
    }
    __syncthreads();   // all MFMA reads of xs rows 0/19 complete before att overwrites them

    // att (tanh, bf16) -> xs dead rows [pixel16x16][9]
    if (m16 < KK) {
        #pragma unroll
        for (int r = 0; r < 2; ++r) {
            #pragma unroll
            for (int reg = 0; reg < 4; ++reg) {
                int pl = (wid * 2 + r) * 16 + lq * 4 + reg;
                xs[att_idx(pl, m16)] = f2bf(tanhf(acc[r][reg]));
            }
        }
    }
    __syncthreads();

    // ---- phase 3: perpix on interior 16x16 (x from xs rows 1..18, att from dead rows) ----
    #pragma unroll
    for (int it = 0; it < 4; ++it) {
        int idx = it * 512 + tid;        // (pl, g): 256 pix x 8 chunks
        int g = idx & 7;
        int pl = idx >> 3;
        int py = pl >> 4, px = pl & 15;  // local 16x16
        int hw = ((h0 + py) << 8) | (w0 + px);

        float a[KK];
        #pragma unroll
        for (int j = 0; j < KK; ++j) a[j] = bf2f(xs[att_idx(pl, j)]);

        float s[8] = {0, 0, 0, 0, 0, 0, 0, 0};
        float xc[8] = {0, 0, 0, 0, 0, 0, 0, 0};
        #pragma unroll
        for (int di = 0; di < 3; ++di) {
            #pragma unroll
            for (int dj = 0; dj < 3; ++dj) {
                int tp = (py + 1 + di) * 20 + (px + 1 + dj);   // xs coords (origin -2), rows 1..18
                int c = g ^ (tp & 7);
                short8 v = *(const short8*)(&xs[(tp << 6) + (c << 3)]);
                float aj = a[di * 3 + dj];
                #pragma unroll
                for (int i = 0; i < 8; ++i) {
                    float xv = bf2f(v[i]);
                    s[i] += xv * aj;
                    if (di == 1 && dj == 1) xc[i] = xv;
                }
            }
        }

        #pragma unroll
        for (int i = 0; i < 8; ++i)
            attf[((b * C_ + g * 8 + i) << 16) | hw] = s[i];

        short8 dv;
        #pragma unroll
        for (int i = 0; i < 8; ++i) dv[i] = (short)f2bf(xc[i] - s[i]);
        *(short8*)(dh + ((size_t)((b << 16) | hw) * 64 + g * 8)) = dv;
    }
}

// ---------------- Kernel E: conv3 (64 -> 9) on d via bf16 MFMA, 512 threads ----------------
__global__ __launch_bounds__(512) void conv3_mfma(
    const unsigned short* __restrict__ dh,   // [B][H][W][64] bf16
    const unsigned short* __restrict__ wb3,  // [9][8][16][8] bf16
    const float* __restrict__ bias,
    unsigned short* __restrict__ r1h)        // [B][9][H][W] bf16
{
    __shared__ __align__(16) unsigned short xs[328 * 64];  // 41984 B (324 pix + 4 pad)

    int tid = threadIdx.x;
    int bx = blockIdx.x & 15;
    int by = (blockIdx.x >> 4) & 15;
    int b  = blockIdx.x >> 8;
    int h0 = by * 16, w0 = bx * 16;
    bool interior = (bx >= 1 && bx <= 14 && by >= 1 && by <= 14);

    int lane = tid & 63;
    int wid  = tid >> 6;      // 0..7

    if (interior) {
        int p = (lane & 7) ^ ((lane >> 3) & 7);
        for (int it = wid; it < 41; it += 8) {     // 328 pixels (4 pad, in-bounds reads)
            int pix = it * 8 + (lane >> 3);
            int py = pix / 18, px = pix - py * 18;
            int gy = h0 + py - 1, gx = w0 + px - 1;
            const unsigned short* g = dh + ((size_t)((b * 256 + gy) * 256 + gx) * 64 + p * 8);
            gld16(g, &xs[it * 512]);
        }
    } else {
        for (int q = tid; q < 324 * 8; q += 512) {
            int p = q & 7;
            int pix = q >> 3;
            int py = pix / 18, px = pix - py * 18;
            int gy = h0 + py - 1, gx = w0 + px - 1;
            short8 v = (short8)0;
            if (gy >= 0 && gy < H_ && gx >= 0 && gx < W_)
                v = *(const short8*)(dh + ((size_t)((b * 256 + gy) * 256 + gx) * 64 + p * 8));
            *(short8*)(&xs[(pix << 6) + ((p ^ (pix & 7)) << 3)]) = v;
        }
    }
    __syncthreads();

    int m16  = lane & 15;
    int lq   = lane >> 4;

    float4_ acc[2];
    float bj = (m16 < KK) ? bias[m16] : 0.f;
    #pragma unroll
    for (int r = 0; r < 2; ++r) acc[r] = (float4_){bj, bj, bj, bj};

    #pragma unroll
    for (int dj = 0; dj < 3; ++dj) {
        short8 bfr[3][2];
        #pragma unroll
        for (int di = 0; di < 3; ++di) {
            int tap = di * 3 + dj;
            bfr[di][0] = *(const short8*)(wb3 + (((tap * 8 + lq) * 16 + m16) * 8));
            bfr[di][1] = *(const short8*)(wb3 + (((tap * 8 + 4 + lq) * 16 + m16) * 8));
        }
        int px = m16 + dj;
        #pragma unroll
        for (int s = 0; s < 4; ++s) {
            int pix = (wid * 2 + s) * 18 + px;
            int c0 = lq ^ (pix & 7);
            short8 a0 = *(const short8*)(&xs[(pix << 6) + (c0 << 3)]);
            short8 a1 = *(const short8*)(&xs[(pix << 6) + ((c0 ^ 4) << 3)]);
            #pragma unroll
            for (int di = 0; di < 3; ++di) {
                int r = s - di;
                if (r < 0 || r > 1) continue;
                acc[r] = __builtin_amdgcn_mfma_f32_16x16x32_bf16(a0, bfr[di][0], acc[r], 0, 0, 0);
                acc[r] = __builtin_amdgcn_mfma_f32_16x16x32_bf16(a1, bfr[di][1], acc[r], 0, 0, 0);
            }
        }
    }

    if (m16 < KK) {
        #pragma unroll
        for (int r = 0; r < 2; ++r) {
            int py = h0 + wid * 2 + r;
            #pragma unroll
            for (int reg = 0; reg < 4; ++reg) {
                int px = w0 + lq * 4 + reg;
                r1h[((b * KK + m16) << 16) | (py << 8) | px] = f2bf(acc[r][reg]);
            }
        }
    }
}

// ---------------- Kernel F: 3x3 conv (9 -> 9) + tanh, bf16 in ----------------
__global__ __launch_bounds__(256) void conv3_tanh9(
    const unsigned short* __restrict__ r1h, const float* __restrict__ w,
    const float* __restrict__ bias, float* __restrict__ out)
{
    const int TW = 32, TH = 8, PW = 34, PH = 10;
    __shared__ float lds[KK][PH][PW];

    int tid = threadIdx.x;
    int tx = tid & 31, ty = tid >> 5;
    int bw = blockIdx.x & 7;
    int bh = (blockIdx.x >> 3) & 31;
    int b  = blockIdx.x >> 8;
    int h0 = bh * TH, w0 = bw * TW;

    for (int idx = tid; idx < KK * PH * PW; idx += 256) {
        int px = idx % PW;
        int py = (idx / PW) % PH;
        int ch = idx / (PW * PH);
        int gy = h0 + py - 1, gx = w0 + px - 1;
        float v = 0.f;
        if (gy >= 0 && gy < H_ && gx >= 0 && gx < W_)
            v = bf2f(r1h[((b * KK + ch) << 16) | (gy << 8) | gx]);
        lds[ch][py][px] = v;
    }
    __syncthreads();

    float acc[KK];
    #pragma unroll
    for (int j = 0; j < KK; ++j) acc[j] = bias[j];

    for (int cin = 0; cin < KK; ++cin) {
        #pragma unroll
        for (int di = 0; di < 3; ++di) {
            #pragma unroll
            for (int dj = 0; dj < 3; ++dj) {
                float xv = lds[cin][ty + di][tx + dj];
                #pragma unroll
                for (int j = 0; j < KK; ++j)
                    acc[j] += xv * w[((j * KK + cin) * 3 + di) * 3 + dj];
            }
        }
    }

    int h = h0 + ty, wq = w0 + tx;
    #pragma unroll
    for (int j = 0; j < KK; ++j)
        out[((b * KK + j) << 16) | (h << 8) | wq] = tanhf(acc[j]);
}

extern "C" void kernel_launch(void* const* d_in, const int* in_sizes, int n_in,
                              void* d_out, int out_size, void* d_ws, size_t ws_size,
                              hipStream_t stream) {
    const float* feature = (const float*)d_in[0];
    const float* w_sharp = (const float*)d_in[1];
    const float* b_sharp = (const float*)d_in[2];
    const float* w_r1    = (const float*)d_in[3];
    const float* b_r1    = (const float*)d_in[4];
    const float* w_r2    = (const float*)d_in[5];
    const float* b_r2    = (const float*)d_in[6];

    float* out_reblur = (float*)d_out;                          // [4,9,256,256]
    float* out_attf   = out_reblur + (size_t)B_ * KK * H_ * W_; // [4,64,256,256]

    char* ws = (char*)d_ws;
    unsigned short* xh   = (unsigned short*)ws;                  // 33554432 B
    unsigned short* dh   = (unsigned short*)(ws + 33554432);     // 33554432 B
    unsigned short* wb   = (unsigned short*)(ws + 67108864);     // 51200 -> pad 65536
    unsigned short* wb3  = (unsigned short*)(ws + 67174400);     // 18432 -> pad 32768
    unsigned short* r1h  = (unsigned short*)(ws + 67207168);     // 4718592 B bf16

    nchw2nhwc<<<1160, 256, 0, stream>>>(feature, xh, w_sharp, w_r1, wb, wb3);
    conv5_perpix<<<1024, 512, 0, stream>>>(xh, wb, b_sharp, out_attf, dh);
    conv3_mfma<<<1024, 512, 0, stream>>>(dh, wb3, b_r1, r1h);
    conv3_tanh9<<<1024, 256, 0, stream>>>(r1h, w_r2, b_r2, out_reblur);
}